// Round 15
// baseline (1036.202 us; speedup 1.0000x reference)
//
#include <hip/hip_runtime.h>

#define DM 128          // model dim
#define KS 20           // attention samples
#define BW 512          // CSR bucket width (nodes)
#define BSH 9           // log2(BW)
#define MAXB 128        // max buckets (N <= 65536)
#define HP 264          // padded LDS hidden row stride (ffn_fused chunk), 16B-aligned

typedef __attribute__((ext_vector_type(8))) short short8;   // 8 bf16 (4 VGPRs)
typedef __attribute__((ext_vector_type(4))) float f32x4;
typedef __attribute__((ext_vector_type(2))) __bf16 bf16x2;

__device__ __forceinline__ unsigned short f2b(float f) {
    unsigned u = __float_as_uint(f);
    u += 0x7fff + ((u >> 16) & 1);          // RNE
    return (unsigned short)(u >> 16);
}
__device__ __forceinline__ float b2f(unsigned short b) {
    return __uint_as_float(((unsigned)b) << 16);
}
__device__ __forceinline__ float blo(unsigned u) { return __uint_as_float(u << 16); }
__device__ __forceinline__ float bhi(unsigned u) { return __uint_as_float(u & 0xffff0000u); }
__device__ __forceinline__ unsigned pk(float a, float b) {
    return (unsigned)f2b(a) | ((unsigned)f2b(b) << 16);
}

// Packed bf16 dot-2 (HW v_dot2_f32_bf16 when available; fallback compile-safe)
#if __has_builtin(__builtin_amdgcn_fdot2_f32_bf16)
__device__ __forceinline__ float dot2bf(unsigned a, unsigned b, float acc) {
    return __builtin_amdgcn_fdot2_f32_bf16(
        __builtin_bit_cast(bf16x2, a), __builtin_bit_cast(bf16x2, b), acc, false);
}
#else
__device__ __forceinline__ float dot2bf(unsigned a, unsigned b, float acc) {
    return acc + blo(a) * blo(b) + bhi(a) * bhi(b);
}
#endif

// ---------------------------------------------------------------------------
// x -> h (fp32 copy) + hb (bf16), float4 wide
// ---------------------------------------------------------------------------
__global__ __launch_bounds__(256) void xcvt_kernel(
    const float* __restrict__ x, float* __restrict__ h,
    unsigned short* __restrict__ hb, int n)
{
    const int i = (blockIdx.x * 256 + threadIdx.x) * 4;
    if (i < n) {
        const float4 v = *(const float4*)(x + i);
        *(float4*)(h + i) = v;
        ((unsigned*)hb)[i / 2]     = pk(v.x, v.y);
        ((unsigned*)hb)[i / 2 + 1] = pk(v.z, v.w);
    }
}

// ---------------------------------------------------------------------------
// Merged setup (R15): weight bf16 convert + WoP repack + bcnt zero in one
// dispatch (removes 2 launches vs wcvt/repack/memset split).
//   tid < 163840           : wcvt float4 chunk i4 = tid*4
//   tid < 163840+24576     : WoP repack (consecutive-k pairs, 2 planes)
//   tid < 163840+24576+128 : bcnt[tid'] = 0
// ---------------------------------------------------------------------------
__global__ __launch_bounds__(256) void setup_kernel(
    const float* __restrict__ t_in_w,  const float* __restrict__ t_out_w,
    const float* __restrict__ t_ffn_w1, const float* __restrict__ t_ffn_w2,
    const float* __restrict__ g_w, unsigned short* __restrict__ wbuf,
    unsigned* __restrict__ WoP, int* __restrict__ bcnt)
{
    const int tid = blockIdx.x * 256 + threadIdx.x;
    if (tid < 163840) {
        const int i4 = tid * 4;
        const float* src; int rel;
        if      (i4 < 147456) { src = t_in_w;   rel = i4; }
        else if (i4 < 196608) { src = t_out_w;  rel = i4 - 147456; }
        else if (i4 < 393216) { src = t_ffn_w1; rel = i4 - 196608; }
        else if (i4 < 589824) { src = t_ffn_w2; rel = i4 - 393216; }
        else                  { src = g_w;      rel = i4 - 589824; }
        const float4 v = *(const float4*)(src + rel);
        ((unsigned*)wbuf)[i4 / 2]     = pk(v.x, v.y);
        ((unsigned*)wbuf)[i4 / 2 + 1] = pk(v.z, v.w);
    } else if (tid < 163840 + 24576) {
        const int t2 = tid - 163840;
        const int i = t2 / 8192, rem = t2 % 8192;
        const int plane = rem >> 12, r2 = rem & 4095;
        const int k2 = r2 >> 6, j = r2 & 63;
        const int col = j + plane * 64;
        const float* W = t_out_w + (size_t)i * 16384;   // [128][128]
        WoP[(size_t)i * 8192 + plane * 4096 + k2 * 64 + j] =
            pk(W[col * 128 + 2 * k2], W[col * 128 + 2 * k2 + 1]);
    } else if (tid < 163840 + 24576 + MAXB) {
        bcnt[tid - 163840 - 24576] = 0;
    }
}

// ---------------------------------------------------------------------------
// MFMA GEMM (bf16 out): out = X@W^T + bias. Block 128x64. (verified R2/R5)
// ---------------------------------------------------------------------------
template <int CI, int CO, bool RELU>
__global__ __launch_bounds__(256) void gemm_mfma(
    const unsigned short* __restrict__ X,
    const unsigned short* __restrict__ W, const float* __restrict__ bias,
    unsigned short* __restrict__ outB, int M)
{
    const int tid  = threadIdx.x;
    const int wave = tid >> 6;
    const int lane = tid & 63;
    const int m0 = blockIdx.x * 128 + (wave >> 1) * 64;
    const int c0 = blockIdx.y * 64 + (wave & 1) * 32;
    const int lrow = lane & 15;
    const int quad = lane >> 4;

    f32x4 acc[4][2];
    #pragma unroll
    for (int i = 0; i < 4; ++i)
        #pragma unroll
        for (int j = 0; j < 2; ++j)
            acc[i][j] = (f32x4){0.f, 0.f, 0.f, 0.f};

    int rr[4]; bool vv[4];
    #pragma unroll
    for (int i = 0; i < 4; ++i) { rr[i] = m0 + i * 16 + lrow; vv[i] = rr[i] < M; }

    #pragma unroll
    for (int k0 = 0; k0 < CI; k0 += 32) {
        const int ko = k0 + quad * 8;
        short8 a[4];
        #pragma unroll
        for (int i = 0; i < 4; ++i) {
            a[i] = short8{};
            if (vv[i]) a[i] = *(const short8*)(X + (size_t)rr[i] * CI + ko);
        }
        const short8 b0 = *(const short8*)(W + (size_t)(c0 + lrow) * CI + ko);
        const short8 b1 = *(const short8*)(W + (size_t)(c0 + 16 + lrow) * CI + ko);
        #pragma unroll
        for (int i = 0; i < 4; ++i) {
            acc[i][0] = __builtin_amdgcn_mfma_f32_16x16x32_bf16(a[i], b0, acc[i][0], 0, 0, 0);
            acc[i][1] = __builtin_amdgcn_mfma_f32_16x16x32_bf16(a[i], b1, acc[i][1], 0, 0, 0);
        }
    }

    #pragma unroll
    for (int i = 0; i < 4; ++i) {
        const int rb = m0 + i * 16 + quad * 4;
        #pragma unroll
        for (int j = 0; j < 2; ++j) {
            const int col = c0 + j * 16 + lrow;
            const float bsv = bias[col];
            #pragma unroll
            for (int r = 0; r < 4; ++r) {
                const int row = rb + r;
                if (row < M) {
                    float v = acc[i][j][r] + bsv;
                    if (RELU) v = fmaxf(v, 0.f);
                    outB[(size_t)row * CO + col] = f2b(v);
                }
            }
        }
    }
}

// ---------------------------------------------------------------------------
// Fused GEMM(CO=128) + residual + LayerNorm. (verified R3-R8)
// ---------------------------------------------------------------------------
template <int CI, bool RELU, int SPLIT>
__global__ __launch_bounds__(256) void gemm_ln(
    const unsigned short* __restrict__ X0, const unsigned short* __restrict__ X1,
    const unsigned short* __restrict__ W, const float* __restrict__ bias,
    const float* __restrict__ resid,
    const float* __restrict__ g, const float* __restrict__ be,
    float* __restrict__ hF, unsigned short* __restrict__ hB, int M)
{
    __shared__ float psum[64][2][2];
    __shared__ float stats[64][2];

    const int tid  = threadIdx.x;
    const int wave = tid >> 6;
    const int lane = tid & 63;
    const int wr = (wave >> 1) * 32;
    const int wc = wave & 1;
    const int m0 = blockIdx.x * 64 + wr;
    const int c0 = wc * 64;
    const int lrow = lane & 15;
    const int quad = lane >> 4;

    f32x4 acc[2][4];
    #pragma unroll
    for (int i = 0; i < 2; ++i)
        #pragma unroll
        for (int j = 0; j < 4; ++j)
            acc[i][j] = (f32x4){0.f, 0.f, 0.f, 0.f};

    const int r0 = m0 + lrow;
    const int r1 = m0 + 16 + lrow;
    const bool v0 = r0 < M, v1 = r1 < M;

    for (int k0 = 0; k0 < CI; k0 += 32) {
        const unsigned short* xs;
        int kk, stride;
        if (SPLIT > 0 && k0 >= SPLIT) { xs = X1; kk = k0 - SPLIT; stride = CI - SPLIT; }
        else                          { xs = X0; kk = k0;         stride = (SPLIT > 0) ? SPLIT : CI; }
        const int ko = kk + quad * 8;
        short8 a0 = {}, a1 = {};
        if (v0) a0 = *(const short8*)(xs + (size_t)r0 * stride + ko);
        if (v1) a1 = *(const short8*)(xs + (size_t)r1 * stride + ko);
        const int kw = k0 + quad * 8;
        #pragma unroll
        for (int j = 0; j < 4; ++j) {
            const short8 bf = *(const short8*)(W + (size_t)(c0 + j * 16 + lrow) * CI + kw);
            acc[0][j] = __builtin_amdgcn_mfma_f32_16x16x32_bf16(a0, bf, acc[0][j], 0, 0, 0);
            acc[1][j] = __builtin_amdgcn_mfma_f32_16x16x32_bf16(a1, bf, acc[1][j], 0, 0, 0);
        }
    }

    float bcol[4], gcol[4], bec[4];
    #pragma unroll
    for (int j = 0; j < 4; ++j) {
        const int col = c0 + j * 16 + lrow;
        bcol[j] = bias[col];
        gcol[j] = g[col];
        bec[j]  = be[col];
    }

    float vals[2][4][4];
    #pragma unroll
    for (int i = 0; i < 2; ++i) {
        #pragma unroll
        for (int r = 0; r < 4; ++r) {
            const int lrel = wr + i * 16 + quad * 4 + r;
            const int row = blockIdx.x * 64 + lrel;
            const bool vr = row < M;
            float s = 0.f, s2 = 0.f;
            #pragma unroll
            for (int j = 0; j < 4; ++j) {
                const int col = c0 + j * 16 + lrow;
                float v = acc[i][j][r] + bcol[j];
                if (RELU) v = fmaxf(v, 0.f);
                if (vr) v += resid[(size_t)row * 128 + col];
                vals[i][j][r] = v;
                s += v; s2 += v * v;
            }
            s  += __shfl_xor(s, 1);  s  += __shfl_xor(s, 2);
            s  += __shfl_xor(s, 4);  s  += __shfl_xor(s, 8);
            s2 += __shfl_xor(s2, 1); s2 += __shfl_xor(s2, 2);
            s2 += __shfl_xor(s2, 4); s2 += __shfl_xor(s2, 8);
            if (lrow == 0) { psum[lrel][wc][0] = s; psum[lrel][wc][1] = s2; }
        }
    }
    __syncthreads();
    if (tid < 64) {
        const float sum   = psum[tid][0][0] + psum[tid][1][0];
        const float sumsq = psum[tid][0][1] + psum[tid][1][1];
        const float mean = sum * (1.f / 128.f);
        const float var  = sumsq * (1.f / 128.f) - mean * mean;
        stats[tid][0] = mean;
        stats[tid][1] = rsqrtf(var + 1e-5f);
    }
    __syncthreads();

    #pragma unroll
    for (int i = 0; i < 2; ++i) {
        #pragma unroll
        for (int r = 0; r < 4; ++r) {
            const int lrel = wr + i * 16 + quad * 4 + r;
            const int row = blockIdx.x * 64 + lrel;
            if (row < M) {
                const float mean = stats[lrel][0];
                const float rstd = stats[lrel][1];
                #pragma unroll
                for (int j = 0; j < 4; ++j) {
                    const int col = c0 + j * 16 + lrow;
                    const float o = (vals[i][j][r] - mean) * rstd * gcol[j] + bec[j];
                    hF[(size_t)row * 128 + col] = o;
                    hB[(size_t)row * 128 + col] = f2b(o);
                }
            }
        }
    }
}

// ---------------------------------------------------------------------------
// Fused FFN v4 (R8, 90us): out = LN( relu(X@W1^T+b1)@W2^T + b2 + resid ).
// Block = 32 rows, 2-chunk K-pipeline through 16.9 KB LDS. In-place safe.
// ---------------------------------------------------------------------------
__global__ __launch_bounds__(256) void ffn_fused(
    const unsigned short* __restrict__ X,    // [M][128] bf16
    const unsigned short* __restrict__ W1,   // [512][128]
    const float* __restrict__ b1,
    const unsigned short* __restrict__ W2,   // [128][512]
    const float* __restrict__ b2,
    const float* __restrict__ resid,
    const float* __restrict__ g, const float* __restrict__ be,
    float* __restrict__ hF, unsigned short* __restrict__ hB, int M)
{
    __shared__ unsigned short Hs[32 * HP];   // 16.9 KB chunk buffer
    __shared__ float psum[32][4][2];
    __shared__ float stats[32][2];

    const int tid  = threadIdx.x;
    const int wave = tid >> 6;
    const int lane = tid & 63;
    const int lrow = lane & 15;
    const int quad = lane >> 4;
    const int m0 = blockIdx.x * 32;

    const int c0 = wave * 32;                // phase-2 col base (32 cols/wave)

    const int r0 = m0 + lrow;
    const int r1 = m0 + 16 + lrow;
    const bool v0 = r0 < M, v1 = r1 < M;

    f32x4 acc2[2][2];
    #pragma unroll
    for (int i = 0; i < 2; ++i)
        #pragma unroll
        for (int j = 0; j < 2; ++j)
            acc2[i][j] = (f32x4){0.f, 0.f, 0.f, 0.f};

    #pragma unroll
    for (int chunk = 0; chunk < 2; ++chunk) {
        const int cb = chunk * 256 + wave * 64;   // global hidden col base
        const int lcb = wave * 64;                // chunk-local col base
        {
            f32x4 acc[2][4];
            #pragma unroll
            for (int i = 0; i < 2; ++i)
                #pragma unroll
                for (int j = 0; j < 4; ++j)
                    acc[i][j] = (f32x4){0.f, 0.f, 0.f, 0.f};

            #pragma unroll
            for (int k0 = 0; k0 < 128; k0 += 32) {
                const int ko = k0 + quad * 8;
                short8 a0 = {}, a1 = {};
                if (v0) a0 = *(const short8*)(X + (size_t)r0 * 128 + ko);
                if (v1) a1 = *(const short8*)(X + (size_t)r1 * 128 + ko);
                #pragma unroll
                for (int j = 0; j < 4; ++j) {
                    const short8 bf = *(const short8*)(W1 + (size_t)(cb + j * 16 + lrow) * 128 + ko);
                    acc[0][j] = __builtin_amdgcn_mfma_f32_16x16x32_bf16(a0, bf, acc[0][j], 0, 0, 0);
                    acc[1][j] = __builtin_amdgcn_mfma_f32_16x16x32_bf16(a1, bf, acc[1][j], 0, 0, 0);
                }
            }
            float bc[4];
            #pragma unroll
            for (int j = 0; j < 4; ++j) bc[j] = b1[cb + j * 16 + lrow];
            #pragma unroll
            for (int i = 0; i < 2; ++i) {
                #pragma unroll
                for (int r = 0; r < 4; ++r) {
                    const int lrel = i * 16 + quad * 4 + r;
                    #pragma unroll
                    for (int j = 0; j < 4; ++j)
                        Hs[lrel * HP + lcb + j * 16 + lrow] =
                            f2b(fmaxf(acc[i][j][r] + bc[j], 0.f));
                }
            }
        }
        __syncthreads();

        #pragma unroll
        for (int k0 = 0; k0 < 256; k0 += 32) {
            const int ko = k0 + quad * 8;                 // chunk-local k
            const int kw = chunk * 256 + ko;              // global k for W2
            const short8 a0 = *(const short8*)&Hs[lrow * HP + ko];
            const short8 a1 = *(const short8*)&Hs[(16 + lrow) * HP + ko];
            #pragma unroll
            for (int j = 0; j < 2; ++j) {
                const short8 bf = *(const short8*)(W2 + (size_t)(c0 + j * 16 + lrow) * 512 + kw);
                acc2[0][j] = __builtin_amdgcn_mfma_f32_16x16x32_bf16(a0, bf, acc2[0][j], 0, 0, 0);
                acc2[1][j] = __builtin_amdgcn_mfma_f32_16x16x32_bf16(a1, bf, acc2[1][j], 0, 0, 0);
            }
        }
        __syncthreads();
    }

    float bcol[2], gcol[2], bec[2];
    #pragma unroll
    for (int j = 0; j < 2; ++j) {
        const int col = c0 + j * 16 + lrow;
        bcol[j] = b2[col];
        gcol[j] = g[col];
        bec[j]  = be[col];
    }

    float vals[2][2][4];
    #pragma unroll
    for (int i = 0; i < 2; ++i) {
        #pragma unroll
        for (int r = 0; r < 4; ++r) {
            const int lrel = i * 16 + quad * 4 + r;
            const int row = m0 + lrel;
            const bool vr = row < M;
            float s = 0.f, s2 = 0.f;
            #pragma unroll
            for (int j = 0; j < 2; ++j) {
                const int col = c0 + j * 16 + lrow;
                float v = acc2[i][j][r] + bcol[j];
                if (vr) v += resid[(size_t)row * 128 + col];
                vals[i][j][r] = v;
                s += v; s2 += v * v;
            }
            s  += __shfl_xor(s, 1);  s  += __shfl_xor(s, 2);
            s  += __shfl_xor(s, 4);  s  += __shfl_xor(s, 8);
            s2 += __shfl_xor(s2, 1); s2 += __shfl_xor(s2, 2);
            s2 += __shfl_xor(s2, 4); s2 += __shfl_xor(s2, 8);
            if (lrow == 0) { psum[lrel][wave][0] = s; psum[lrel][wave][1] = s2; }
        }
    }
    __syncthreads();
    if (tid < 32) {
        const float sum   = psum[tid][0][0] + psum[tid][1][0] + psum[tid][2][0] + psum[tid][3][0];
        const float sumsq = psum[tid][0][1] + psum[tid][1][1] + psum[tid][2][1] + psum[tid][3][1];
        const float mean = sum * (1.f / 128.f);
        const float var  = sumsq * (1.f / 128.f) - mean * mean;
        stats[tid][0] = mean;
        stats[tid][1] = rsqrtf(var + 1e-5f);
    }
    __syncthreads();

    #pragma unroll
    for (int i = 0; i < 2; ++i) {
        #pragma unroll
        for (int r = 0; r < 4; ++r) {
            const int lrel = i * 16 + quad * 4 + r;
            const int row = m0 + lrel;
            if (row < M) {
                const float mean = stats[lrel][0];
                const float rstd = stats[lrel][1];
                #pragma unroll
                for (int j = 0; j < 2; ++j) {
                    const int col = c0 + j * 16 + lrow;
                    const float o = (vals[i][j][r] - mean) * rstd * gcol[j] + bec[j];
                    hF[(size_t)row * 128 + col] = o;
                    hB[(size_t)row * 128 + col] = f2b(o);
                }
            }
        }
    }
}

// ---------------------------------------------------------------------------
// attn_fused = sampled attention + out-proj + resid + LN1 (verified R13/R14).
// R15: own-row resid loads issued BEFORE the sample gathers (latency hidden).
// ---------------------------------------------------------------------------
__global__ __launch_bounds__(256) void attn_fused(
    const unsigned short* __restrict__ qkv, const int* __restrict__ samples,
    const unsigned* __restrict__ WoP,   // [2 planes][64 k2][64 j] packed pairs
    const float* __restrict__ bo,
    const float* __restrict__ g, const float* __restrict__ be,
    float* __restrict__ hF, unsigned short* __restrict__ hB, int n)
{
    __shared__ unsigned ctxs[4][64];    // packed bf16 ctx pairs per wave
    const int wv = threadIdx.x >> 6;
    const int lane = threadIdx.x & 63;
    const int node0 = blockIdx.x * 4 + wv;
    const bool live = node0 < n;
    const int node = live ? node0 : (n - 1);   // clamp; stores guarded by live
    const int s4 = lane >> 4;
    const int p  = lane & 15;
    const float scale = 0.17677669529663687f;  // 1/sqrt(32)

    // prefetch own-row residual (consumed only after the matvec)
    const size_t base = (size_t)node * 128;
    const float res0 = hF[base + lane];
    const float res1 = hF[base + lane + 64];

    const uint4 qu = *(const uint4*)(qkv + (size_t)node * 384 + p * 8);

    int rows[5];
    #pragma unroll
    for (int jj = 0; jj < 5; ++jj)
        rows[jj] = samples[node * KS + jj * 4 + s4];

    uint4 kus[5], vus[5];
    #pragma unroll
    for (int jj = 0; jj < 5; ++jj) {
        const size_t rb = (size_t)rows[jj] * 384 + p * 8;
        kus[jj] = *(const uint4*)(qkv + rb + 128);
        vus[jj] = *(const uint4*)(qkv + rb + 256);
    }

    float sc[5];
    #pragma unroll
    for (int jj = 0; jj < 5; ++jj) {
        const uint4 ku = kus[jj];
        float d = dot2bf(qu.x, ku.x, 0.f);
        d = dot2bf(qu.y, ku.y, d);
        d = dot2bf(qu.z, ku.z, d);
        d = dot2bf(qu.w, ku.w, d);
        d += __shfl_xor(d, 1);
        d += __shfl_xor(d, 2);
        sc[jj] = d * scale;
    }

    float m = sc[0];
    #pragma unroll
    for (int jj = 1; jj < 5; ++jj) m = fmaxf(m, sc[jj]);
    m = fmaxf(m, __shfl_xor(m, 16));
    m = fmaxf(m, __shfl_xor(m, 32));

    float l = 0.f;
    float o[8] = {};
    #pragma unroll
    for (int jj = 0; jj < 5; ++jj) {
        const float e = __expf(sc[jj] - m);
        l += e;
        const uint4 vu = vus[jj];
        o[0] += e * blo(vu.x); o[1] += e * bhi(vu.x);
        o[2] += e * blo(vu.y); o[3] += e * bhi(vu.y);
        o[4] += e * blo(vu.z); o[5] += e * bhi(vu.z);
        o[6] += e * blo(vu.w); o[7] += e * bhi(vu.w);
    }

    l += __shfl_xor(l, 16); l += __shfl_xor(l, 32);
    #pragma unroll
    for (int i = 0; i < 8; ++i) {
        o[i] += __shfl_xor(o[i], 16);
        o[i] += __shfl_xor(o[i], 32);
    }

    const float inv = 1.f / l;
    if (s4 == 0) {
        #pragma unroll
        for (int i = 0; i < 4; ++i)
            ctxs[wv][p * 4 + i] = pk(o[2 * i] * inv, o[2 * i + 1] * inv);
    }
    __syncthreads();

    // ---- out-proj matvec: lane -> cols {lane, lane+64}, dot2 ----
    const unsigned* Wa = WoP;           // cols 0..63
    const unsigned* Wb = WoP + 4096;    // cols 64..127
    float a0 = 0.f, a1 = 0.f;
    #pragma unroll 8
    for (int k2 = 0; k2 < 64; ++k2) {
        const unsigned c = ctxs[wv][k2];
        a0 = dot2bf(Wa[k2 * 64 + lane], c, a0);
        a1 = dot2bf(Wb[k2 * 64 + lane], c, a1);
    }

    // ---- resid + LN (verified resln pattern: lane / lane+64) ----
    float v0 = a0 + bo[lane]      + res0;
    float v1 = a1 + bo[lane + 64] + res1;
    float s = v0 + v1;
    #pragma unroll
    for (int mm = 32; mm >= 1; mm >>= 1) s += __shfl_xor(s, mm, 64);
    const float mean = s * (1.f / 128.f);
    const float d0 = v0 - mean, d1 = v1 - mean;
    float vs = d0 * d0 + d1 * d1;
    #pragma unroll
    for (int mm = 32; mm >= 1; mm >>= 1) vs += __shfl_xor(vs, mm, 64);
    const float rstd = rsqrtf(vs * (1.f / 128.f) + 1e-5f);
    if (live) {
        const float o0 = d0 * rstd * g[lane]      + be[lane];
        const float o1 = d1 * rstd * g[lane + 64] + be[lane + 64];
        hF[base + lane]      = o0;      hF[base + lane + 64] = o1;
        hB[base + lane]      = f2b(o0); hB[base + lane + 64] = f2b(o1);
    }
}

// ---------------------------------------------------------------------------
// Aggregation: wave/node, 4 edge slots x 8-deep unroll (32 loads in flight).
// (R15: deepened from 16 — agg was the lowest-MLP gather, VALUBusy 15%)
// ---------------------------------------------------------------------------
__global__ __launch_bounds__(256) void aggregate_kernel(
    const unsigned short* __restrict__ hb, const int* __restrict__ offs,
    const int* __restrict__ csr, unsigned short* __restrict__ outp, int n, int E)
{
    const int node = blockIdx.x * 4 + (threadIdx.x >> 6);
    const int lane = threadIdx.x & 63;
    if (node >= n) return;
    const int e4 = lane >> 4;
    const int p  = lane & 15;
    const int s = offs[node];
    const int e = (node == n - 1) ? E : offs[node + 1];
    float a[8] = {};
    int i = s + e4;
    for (; i + 28 < e; i += 32) {
        uint4 u[8];
        #pragma unroll
        for (int q = 0; q < 8; ++q) {
            const int d = csr[i + q * 4];
            u[q] = *(const uint4*)(hb + (size_t)d * 128 + p * 8);
        }
        #pragma unroll
        for (int q = 0; q < 8; ++q) {
            a[0] += blo(u[q].x); a[1] += bhi(u[q].x);
            a[2] += blo(u[q].y); a[3] += bhi(u[q].y);
            a[4] += blo(u[q].z); a[5] += bhi(u[q].z);
            a[6] += blo(u[q].w); a[7] += bhi(u[q].w);
        }
    }
    for (; i < e; i += 4) {
        const uint4 u = *(const uint4*)(hb + (size_t)csr[i] * 128 + p * 8);
        a[0] += blo(u.x); a[1] += bhi(u.x);
        a[2] += blo(u.y); a[3] += bhi(u.y);
        a[4] += blo(u.z); a[5] += bhi(u.z);
        a[6] += blo(u.w); a[7] += bhi(u.w);
    }
    #pragma unroll
    for (int k = 0; k < 8; ++k) {
        a[k] += __shfl_xor(a[k], 16);
        a[k] += __shfl_xor(a[k], 32);
    }
    if (e4 == 0) {
        uint4 ow;
        ow.x = pk(a[0], a[1]); ow.y = pk(a[2], a[3]);
        ow.z = pk(a[4], a[5]); ow.w = pk(a[6], a[7]);
        *(uint4*)(outp + (size_t)node * 128 + p * 8) = ow;
    }
}

// ---------------------------------------------------------------------------
// Bucketed CSR build. (verified R4)
// ---------------------------------------------------------------------------
__global__ __launch_bounds__(256) void bcount_kernel(
    const int* __restrict__ esrc, int* __restrict__ bcnt, int E)
{
    __shared__ int hist[MAXB];
    for (int i = threadIdx.x; i < MAXB; i += 256) hist[i] = 0;
    __syncthreads();
    const int stride = gridDim.x * 256;
    for (int e = blockIdx.x * 256 + threadIdx.x; e < E; e += stride)
        atomicAdd(&hist[esrc[e] >> BSH], 1);
    __syncthreads();
    for (int i = threadIdx.x; i < MAXB; i += 256)
        if (hist[i]) atomicAdd(&bcnt[i], hist[i]);
}

__global__ void bscan_kernel(const int* __restrict__ bcnt, int* __restrict__ boffs,
                             int* __restrict__ bcur, int NB)
{
    if (threadIdx.x == 0 && blockIdx.x == 0) {
        int run = 0;
        for (int i = 0; i < NB; ++i) { boffs[i] = run; bcur[i] = run; run += bcnt[i]; }
        boffs[NB] = run;
    }
}

__global__ __launch_bounds__(256) void bscatter_kernel(
    const int* __restrict__ esrc, const int* __restrict__ edst,
    int* __restrict__ bcur, uint2* __restrict__ ebuck, int E)
{
    __shared__ int hist[MAXB], scanb[MAXB], lstart[MAXB], gbase[MAXB], cnt2[MAXB];
    __shared__ uint2 stage[2048];
    __shared__ int gaddr[2048];
    const int t = threadIdx.x;
    const int base = blockIdx.x * 2048;
    const int nchunk = min(2048, E - base);
    for (int i = t; i < MAXB; i += 256) { hist[i] = 0; cnt2[i] = 0; }
    __syncthreads();

    int es[8], ed[8], eb[8];
    #pragma unroll
    for (int i = 0; i < 8; ++i) {
        const int idx = base + i * 256 + t;
        if (idx < E) {
            es[i] = esrc[idx]; ed[i] = edst[idx];
            eb[i] = es[i] >> BSH;
            atomicAdd(&hist[eb[i]], 1);
        } else eb[i] = -1;
    }
    __syncthreads();

    if (t < MAXB) scanb[t] = hist[t];
    __syncthreads();
    for (int off = 1; off < MAXB; off <<= 1) {
        int v = 0;
        if (t < MAXB && t >= off) v = scanb[t - off];
        __syncthreads();
        if (t < MAXB) scanb[t] += v;
        __syncthreads();
    }
    if (t < MAXB) {
        lstart[t] = scanb[t] - hist[t];
        if (hist[t] > 0) gbase[t] = atomicAdd(&bcur[t], hist[t]);
    }
    __syncthreads();

    #pragma unroll
    for (int i = 0; i < 8; ++i) {
        if (eb[i] >= 0) {
            const int li = atomicAdd(&cnt2[eb[i]], 1);
            const int pos = lstart[eb[i]] + li;
            stage[pos] = make_uint2((unsigned)es[i], (unsigned)ed[i]);
            gaddr[pos] = gbase[eb[i]] + li;
        }
    }
    __syncthreads();
    for (int i = t; i < nchunk; i += 256)
        ebuck[gaddr[i]] = stage[i];
}

__global__ __launch_bounds__(256) void bbuild_kernel(
    const uint2* __restrict__ ebuck, const int* __restrict__ bcnt,
    const int* __restrict__ boffs, int* __restrict__ offs, int* __restrict__ csr, int N)
{
    __shared__ int degl[BW], sbuf[BW], curl[BW];
    const int b = blockIdx.x;
    const int t = threadIdx.x;
    const int nbase = b * BW;
    const int nn = min(BW, N - nbase);
    const int estart = boffs[b];
    const int ecnt = bcnt[b];

    for (int i = t; i < BW; i += 256) { degl[i] = 0; curl[i] = 0; }
    __syncthreads();
    for (int i = t; i < ecnt; i += 256)
        atomicAdd(&degl[(int)ebuck[estart + i].x - nbase], 1);
    __syncthreads();

    sbuf[t] = degl[t]; sbuf[t + 256] = degl[t + 256];
    __syncthreads();
    for (int off = 1; off < BW; off <<= 1) {
        const int i1 = t + 256;
        int v0 = (t  >= off) ? sbuf[t  - off] : 0;
        int v1 = (i1 >= off) ? sbuf[i1 - off] : 0;
        __syncthreads();
        sbuf[t] += v0; sbuf[i1] += v1;
        __syncthreads();
    }
    {
        const int e0 = sbuf[t] - degl[t];
        const int e1 = sbuf[t + 256] - degl[t + 256];
        sbuf[t] = e0; sbuf[t + 256] = e1;
        if (t < nn)       offs[nbase + t]       = estart + e0;
        if (t + 256 < nn) offs[nbase + t + 256] = estart + e1;
    }
    __syncthreads();
    for (int i = t; i < ecnt; i += 256) {
        const uint2 pr = ebuck[estart + i];
        const int s = (int)pr.x - nbase;
        const int pos = estart + sbuf[s] + atomicAdd(&curl[s], 1);
        csr[pos] = (int)pr.y;
    }
}

// ---------------------------------------------------------------------------
extern "C" void kernel_launch(void* const* d_in, const int* in_sizes, int n_in,
                              void* d_out, int out_size, void* d_ws, size_t ws_size,
                              hipStream_t stream)
{
    const float* x        = (const float*)d_in[0];
    const int*   samples  = (const int*)d_in[1];
    const int*   esrc     = (const int*)d_in[2];
    const int*   edst     = (const int*)d_in[3];
    const float* t_in_w   = (const float*)d_in[4];   // [3][384][128]
    const float* t_in_b   = (const float*)d_in[5];
    const float* t_out_w  = (const float*)d_in[6];   // [3][128][128]
    const float* t_out_b  = (const float*)d_in[7];
    const float* t_ffn_w1 = (const float*)d_in[8];   // [3][512][128]
    const float* t_ffn_b1 = (const float*)d_in[9];
    const float* t_ffn_w2 = (const float*)d_in[10];  // [3][128][512]
    const float* t_ffn_b2 = (const float*)d_in[11];
    const float* t_ln1_g  = (const float*)d_in[12];
    const float* t_ln1_b  = (const float*)d_in[13];
    const float* t_ln2_g  = (const float*)d_in[14];
    const float* t_ln2_b  = (const float*)d_in[15];
    const float* g_w      = (const float*)d_in[16];  // [2][128][256]
    const float* g_b      = (const float*)d_in[17];
    const float* g_ln_g   = (const float*)d_in[18];
    const float* g_ln_b   = (const float*)d_in[19];

    const int N = in_sizes[0] / DM;
    const int E = in_sizes[2];
    const int NB = (N + BW - 1) >> BSH;

    float* h = (float*)d_out;                        // [N][128] fp32 hidden

    // ---- workspace layout ----
    unsigned short* wbuf = (unsigned short*)d_ws;    // bf16 weights
    unsigned short* w_in  = wbuf;                    // 3*384*128 = 147456
    unsigned short* w_out = w_in  + 147456;          // 3*128*128 = 49152 (unused)
    unsigned short* w_f1  = w_out + 49152;           // 3*512*128 = 196608
    unsigned short* w_f2  = w_f1  + 196608;          // 3*128*512 = 196608
    unsigned short* w_g   = w_f2  + 196608;          // 2*128*256 = 65536
    unsigned* WoP = (unsigned*)(w_g + 65536);        // 3*8192 uints (packed pairs)
    unsigned short* hb  = (unsigned short*)(WoP + 3 * 8192);   // [N][128] bf16
    unsigned short* Bbf = hb  + (size_t)N * 128;     // [N][128] neigh
    unsigned short* Abf = Bbf + (size_t)N * 128;     // [N][384] QKV
    uint2* ebuck = (uint2*)(Abf + (size_t)N * 384);  // [E]
    int* offs = (int*)(ebuck + E);                   // [N]
    int* csr  = offs + N;                            // [E]
    int* bcnt  = csr + E;                            // [MAXB]
    int* boffs = bcnt + MAXB;                        // [MAXB+1]
    int* bcur  = boffs + MAXB + 1;                   // [MAXB]

    const int mt  = (N + 63) / 64;
    const int mt2 = (N + 127) / 128;
    const int mtf = (N + 31) / 32;
    const dim3 blk(256);

    xcvt_kernel<<<((N * DM) / 4 + 255) / 256, blk, 0, stream>>>(x, h, hb, N * DM);
    setup_kernel<<<(163840 + 24576 + MAXB + 255) / 256, blk, 0, stream>>>(
        t_in_w, t_out_w, t_ffn_w1, t_ffn_w2, g_w, wbuf, WoP, bcnt);

    // ---- bucketed CSR build (bcnt zeroed by setup_kernel) ----
    bcount_kernel<<<(E + 2047) / 2048, blk, 0, stream>>>(esrc, bcnt, E);
    bscan_kernel<<<1, 64, 0, stream>>>(bcnt, boffs, bcur, NB);
    bscatter_kernel<<<(E + 2047) / 2048, blk, 0, stream>>>(esrc, edst, bcur, ebuck, E);
    bbuild_kernel<<<NB, blk, 0, stream>>>(ebuck, bcnt, boffs, offs, csr, N);

    const int pn_grid = (N + 3) / 4;

    for (int layer = 0; layer < 5; ++layer) {
        if (layer == 1 || layer == 3) {
            // -------- GNN block: split (R14 — fused variant was slower) -----
            const int i = (layer == 1) ? 0 : 1;
            aggregate_kernel<<<pn_grid, blk, 0, stream>>>(hb, offs, csr, Bbf, N, E);
            gemm_ln<256, true, 128><<<mt, blk, 0, stream>>>(
                hb, Bbf, w_g + (size_t)i * 32768, g_b + i * 128, h,
                g_ln_g + i * 128, g_ln_b + i * 128, h, hb, N);
        } else {
            // ---------------- Transformer block: 3 kernels ----------------
            const int i = (layer == 0) ? 0 : (layer == 2 ? 1 : 2);
            gemm_mfma<128, 384, false><<<dim3(mt2, 6), blk, 0, stream>>>(
                hb, w_in + (size_t)i * 49152, t_in_b + i * 384, Abf, N);
            attn_fused<<<pn_grid, blk, 0, stream>>>(
                Abf, samples, WoP + (size_t)i * 8192, t_out_b + i * 128,
                t_ln1_g + i * 128, t_ln1_b + i * 128, h, hb, N);
            ffn_fused<<<mtf, blk, 0, stream>>>(
                hb, w_f1 + (size_t)i * 65536, t_ffn_b1 + i * 512,
                w_f2 + (size_t)i * 65536, t_ffn_b2 + i * 128, h,
                t_ln2_g + i * 128, t_ln2_b + i * 128, h, hb, N);
        }
    }
}

// Round 16
// 1003.978 us; speedup vs baseline: 1.0321x; 1.0321x over previous
//
#include <hip/hip_runtime.h>

#define DM 128          // model dim
#define KS 20           // attention samples
#define BW 512          // CSR bucket width (nodes)
#define BSH 9           // log2(BW)
#define MAXB 128        // max buckets (N <= 65536)
#define HP 264          // padded LDS hidden row stride (ffn_fused chunk), 16B-aligned

typedef __attribute__((ext_vector_type(8))) short short8;   // 8 bf16 (4 VGPRs)
typedef __attribute__((ext_vector_type(4))) float f32x4;
typedef __attribute__((ext_vector_type(2))) __bf16 bf16x2;

__device__ __forceinline__ unsigned short f2b(float f) {
    unsigned u = __float_as_uint(f);
    u += 0x7fff + ((u >> 16) & 1);          // RNE
    return (unsigned short)(u >> 16);
}
__device__ __forceinline__ float b2f(unsigned short b) {
    return __uint_as_float(((unsigned)b) << 16);
}
__device__ __forceinline__ float blo(unsigned u) { return __uint_as_float(u << 16); }
__device__ __forceinline__ float bhi(unsigned u) { return __uint_as_float(u & 0xffff0000u); }
__device__ __forceinline__ unsigned pk(float a, float b) {
    return (unsigned)f2b(a) | ((unsigned)f2b(b) << 16);
}

// Packed bf16 dot-2 (HW v_dot2_f32_bf16 when available; fallback compile-safe)
#if __has_builtin(__builtin_amdgcn_fdot2_f32_bf16)
__device__ __forceinline__ float dot2bf(unsigned a, unsigned b, float acc) {
    return __builtin_amdgcn_fdot2_f32_bf16(
        __builtin_bit_cast(bf16x2, a), __builtin_bit_cast(bf16x2, b), acc, false);
}
#else
__device__ __forceinline__ float dot2bf(unsigned a, unsigned b, float acc) {
    return acc + blo(a) * blo(b) + bhi(a) * bhi(b);
}
#endif

// ---------------------------------------------------------------------------
// x -> h (fp32 copy) + hb (bf16), float4 wide
// ---------------------------------------------------------------------------
__global__ __launch_bounds__(256) void xcvt_kernel(
    const float* __restrict__ x, float* __restrict__ h,
    unsigned short* __restrict__ hb, int n)
{
    const int i = (blockIdx.x * 256 + threadIdx.x) * 4;
    if (i < n) {
        const float4 v = *(const float4*)(x + i);
        *(float4*)(h + i) = v;
        ((unsigned*)hb)[i / 2]     = pk(v.x, v.y);
        ((unsigned*)hb)[i / 2 + 1] = pk(v.z, v.w);
    }
}

// ---------------------------------------------------------------------------
// Merged setup (R15): weight bf16 convert + WoP repack + bcnt zero.
// ---------------------------------------------------------------------------
__global__ __launch_bounds__(256) void setup_kernel(
    const float* __restrict__ t_in_w,  const float* __restrict__ t_out_w,
    const float* __restrict__ t_ffn_w1, const float* __restrict__ t_ffn_w2,
    const float* __restrict__ g_w, unsigned short* __restrict__ wbuf,
    unsigned* __restrict__ WoP, int* __restrict__ bcnt)
{
    const int tid = blockIdx.x * 256 + threadIdx.x;
    if (tid < 163840) {
        const int i4 = tid * 4;
        const float* src; int rel;
        if      (i4 < 147456) { src = t_in_w;   rel = i4; }
        else if (i4 < 196608) { src = t_out_w;  rel = i4 - 147456; }
        else if (i4 < 393216) { src = t_ffn_w1; rel = i4 - 196608; }
        else if (i4 < 589824) { src = t_ffn_w2; rel = i4 - 393216; }
        else                  { src = g_w;      rel = i4 - 589824; }
        const float4 v = *(const float4*)(src + rel);
        ((unsigned*)wbuf)[i4 / 2]     = pk(v.x, v.y);
        ((unsigned*)wbuf)[i4 / 2 + 1] = pk(v.z, v.w);
    } else if (tid < 163840 + 24576) {
        const int t2 = tid - 163840;
        const int i = t2 / 8192, rem = t2 % 8192;
        const int plane = rem >> 12, r2 = rem & 4095;
        const int k2 = r2 >> 6, j = r2 & 63;
        const int col = j + plane * 64;
        const float* W = t_out_w + (size_t)i * 16384;   // [128][128]
        WoP[(size_t)i * 8192 + plane * 4096 + k2 * 64 + j] =
            pk(W[col * 128 + 2 * k2], W[col * 128 + 2 * k2 + 1]);
    } else if (tid < 163840 + 24576 + MAXB) {
        bcnt[tid - 163840 - 24576] = 0;
    }
}

// ---------------------------------------------------------------------------
// MFMA GEMM (bf16 out): out = X@W^T + bias. Block 128x64. (verified R2/R5)
// ---------------------------------------------------------------------------
template <int CI, int CO, bool RELU>
__global__ __launch_bounds__(256) void gemm_mfma(
    const unsigned short* __restrict__ X,
    const unsigned short* __restrict__ W, const float* __restrict__ bias,
    unsigned short* __restrict__ outB, int M)
{
    const int tid  = threadIdx.x;
    const int wave = tid >> 6;
    const int lane = tid & 63;
    const int m0 = blockIdx.x * 128 + (wave >> 1) * 64;
    const int c0 = blockIdx.y * 64 + (wave & 1) * 32;
    const int lrow = lane & 15;
    const int quad = lane >> 4;

    f32x4 acc[4][2];
    #pragma unroll
    for (int i = 0; i < 4; ++i)
        #pragma unroll
        for (int j = 0; j < 2; ++j)
            acc[i][j] = (f32x4){0.f, 0.f, 0.f, 0.f};

    int rr[4]; bool vv[4];
    #pragma unroll
    for (int i = 0; i < 4; ++i) { rr[i] = m0 + i * 16 + lrow; vv[i] = rr[i] < M; }

    #pragma unroll
    for (int k0 = 0; k0 < CI; k0 += 32) {
        const int ko = k0 + quad * 8;
        short8 a[4];
        #pragma unroll
        for (int i = 0; i < 4; ++i) {
            a[i] = short8{};
            if (vv[i]) a[i] = *(const short8*)(X + (size_t)rr[i] * CI + ko);
        }
        const short8 b0 = *(const short8*)(W + (size_t)(c0 + lrow) * CI + ko);
        const short8 b1 = *(const short8*)(W + (size_t)(c0 + 16 + lrow) * CI + ko);
        #pragma unroll
        for (int i = 0; i < 4; ++i) {
            acc[i][0] = __builtin_amdgcn_mfma_f32_16x16x32_bf16(a[i], b0, acc[i][0], 0, 0, 0);
            acc[i][1] = __builtin_amdgcn_mfma_f32_16x16x32_bf16(a[i], b1, acc[i][1], 0, 0, 0);
        }
    }

    #pragma unroll
    for (int i = 0; i < 4; ++i) {
        const int rb = m0 + i * 16 + quad * 4;
        #pragma unroll
        for (int j = 0; j < 2; ++j) {
            const int col = c0 + j * 16 + lrow;
            const float bsv = bias[col];
            #pragma unroll
            for (int r = 0; r < 4; ++r) {
                const int row = rb + r;
                if (row < M) {
                    float v = acc[i][j][r] + bsv;
                    if (RELU) v = fmaxf(v, 0.f);
                    outB[(size_t)row * CO + col] = f2b(v);
                }
            }
        }
    }
}

// ---------------------------------------------------------------------------
// Fused GEMM(CO=128) + residual + LayerNorm. (verified R3-R8)
// ---------------------------------------------------------------------------
template <int CI, bool RELU, int SPLIT>
__global__ __launch_bounds__(256) void gemm_ln(
    const unsigned short* __restrict__ X0, const unsigned short* __restrict__ X1,
    const unsigned short* __restrict__ W, const float* __restrict__ bias,
    const float* __restrict__ resid,
    const float* __restrict__ g, const float* __restrict__ be,
    float* __restrict__ hF, unsigned short* __restrict__ hB, int M)
{
    __shared__ float psum[64][2][2];
    __shared__ float stats[64][2];

    const int tid  = threadIdx.x;
    const int wave = tid >> 6;
    const int lane = tid & 63;
    const int wr = (wave >> 1) * 32;
    const int wc = wave & 1;
    const int m0 = blockIdx.x * 64 + wr;
    const int c0 = wc * 64;
    const int lrow = lane & 15;
    const int quad = lane >> 4;

    f32x4 acc[2][4];
    #pragma unroll
    for (int i = 0; i < 2; ++i)
        #pragma unroll
        for (int j = 0; j < 4; ++j)
            acc[i][j] = (f32x4){0.f, 0.f, 0.f, 0.f};

    const int r0 = m0 + lrow;
    const int r1 = m0 + 16 + lrow;
    const bool v0 = r0 < M, v1 = r1 < M;

    for (int k0 = 0; k0 < CI; k0 += 32) {
        const unsigned short* xs;
        int kk, stride;
        if (SPLIT > 0 && k0 >= SPLIT) { xs = X1; kk = k0 - SPLIT; stride = CI - SPLIT; }
        else                          { xs = X0; kk = k0;         stride = (SPLIT > 0) ? SPLIT : CI; }
        const int ko = kk + quad * 8;
        short8 a0 = {}, a1 = {};
        if (v0) a0 = *(const short8*)(xs + (size_t)r0 * stride + ko);
        if (v1) a1 = *(const short8*)(xs + (size_t)r1 * stride + ko);
        const int kw = k0 + quad * 8;
        #pragma unroll
        for (int j = 0; j < 4; ++j) {
            const short8 bf = *(const short8*)(W + (size_t)(c0 + j * 16 + lrow) * CI + kw);
            acc[0][j] = __builtin_amdgcn_mfma_f32_16x16x32_bf16(a0, bf, acc[0][j], 0, 0, 0);
            acc[1][j] = __builtin_amdgcn_mfma_f32_16x16x32_bf16(a1, bf, acc[1][j], 0, 0, 0);
        }
    }

    float bcol[4], gcol[4], bec[4];
    #pragma unroll
    for (int j = 0; j < 4; ++j) {
        const int col = c0 + j * 16 + lrow;
        bcol[j] = bias[col];
        gcol[j] = g[col];
        bec[j]  = be[col];
    }

    float vals[2][4][4];
    #pragma unroll
    for (int i = 0; i < 2; ++i) {
        #pragma unroll
        for (int r = 0; r < 4; ++r) {
            const int lrel = wr + i * 16 + quad * 4 + r;
            const int row = blockIdx.x * 64 + lrel;
            const bool vr = row < M;
            float s = 0.f, s2 = 0.f;
            #pragma unroll
            for (int j = 0; j < 4; ++j) {
                const int col = c0 + j * 16 + lrow;
                float v = acc[i][j][r] + bcol[j];
                if (RELU) v = fmaxf(v, 0.f);
                if (vr) v += resid[(size_t)row * 128 + col];
                vals[i][j][r] = v;
                s += v; s2 += v * v;
            }
            s  += __shfl_xor(s, 1);  s  += __shfl_xor(s, 2);
            s  += __shfl_xor(s, 4);  s  += __shfl_xor(s, 8);
            s2 += __shfl_xor(s2, 1); s2 += __shfl_xor(s2, 2);
            s2 += __shfl_xor(s2, 4); s2 += __shfl_xor(s2, 8);
            if (lrow == 0) { psum[lrel][wc][0] = s; psum[lrel][wc][1] = s2; }
        }
    }
    __syncthreads();
    if (tid < 64) {
        const float sum   = psum[tid][0][0] + psum[tid][1][0];
        const float sumsq = psum[tid][0][1] + psum[tid][1][1];
        const float mean = sum * (1.f / 128.f);
        const float var  = sumsq * (1.f / 128.f) - mean * mean;
        stats[tid][0] = mean;
        stats[tid][1] = rsqrtf(var + 1e-5f);
    }
    __syncthreads();

    #pragma unroll
    for (int i = 0; i < 2; ++i) {
        #pragma unroll
        for (int r = 0; r < 4; ++r) {
            const int lrel = wr + i * 16 + quad * 4 + r;
            const int row = blockIdx.x * 64 + lrel;
            if (row < M) {
                const float mean = stats[lrel][0];
                const float rstd = stats[lrel][1];
                #pragma unroll
                for (int j = 0; j < 4; ++j) {
                    const int col = c0 + j * 16 + lrow;
                    const float o = (vals[i][j][r] - mean) * rstd * gcol[j] + bec[j];
                    hF[(size_t)row * 128 + col] = o;
                    hB[(size_t)row * 128 + col] = f2b(o);
                }
            }
        }
    }
}

// ---------------------------------------------------------------------------
// Fused FFN v4 (R8, 90us): out = LN( relu(X@W1^T+b1)@W2^T + b2 + resid ).
// Block = 32 rows, 2-chunk K-pipeline through 16.9 KB LDS. In-place safe.
// ---------------------------------------------------------------------------
__global__ __launch_bounds__(256) void ffn_fused(
    const unsigned short* __restrict__ X,    // [M][128] bf16
    const unsigned short* __restrict__ W1,   // [512][128]
    const float* __restrict__ b1,
    const unsigned short* __restrict__ W2,   // [128][512]
    const float* __restrict__ b2,
    const float* __restrict__ resid,
    const float* __restrict__ g, const float* __restrict__ be,
    float* __restrict__ hF, unsigned short* __restrict__ hB, int M)
{
    __shared__ unsigned short Hs[32 * HP];   // 16.9 KB chunk buffer
    __shared__ float psum[32][4][2];
    __shared__ float stats[32][2];

    const int tid  = threadIdx.x;
    const int wave = tid >> 6;
    const int lane = tid & 63;
    const int lrow = lane & 15;
    const int quad = lane >> 4;
    const int m0 = blockIdx.x * 32;

    const int c0 = wave * 32;                // phase-2 col base (32 cols/wave)

    const int r0 = m0 + lrow;
    const int r1 = m0 + 16 + lrow;
    const bool v0 = r0 < M, v1 = r1 < M;

    f32x4 acc2[2][2];
    #pragma unroll
    for (int i = 0; i < 2; ++i)
        #pragma unroll
        for (int j = 0; j < 2; ++j)
            acc2[i][j] = (f32x4){0.f, 0.f, 0.f, 0.f};

    #pragma unroll
    for (int chunk = 0; chunk < 2; ++chunk) {
        const int cb = chunk * 256 + wave * 64;   // global hidden col base
        const int lcb = wave * 64;                // chunk-local col base
        {
            f32x4 acc[2][4];
            #pragma unroll
            for (int i = 0; i < 2; ++i)
                #pragma unroll
                for (int j = 0; j < 4; ++j)
                    acc[i][j] = (f32x4){0.f, 0.f, 0.f, 0.f};

            #pragma unroll
            for (int k0 = 0; k0 < 128; k0 += 32) {
                const int ko = k0 + quad * 8;
                short8 a0 = {}, a1 = {};
                if (v0) a0 = *(const short8*)(X + (size_t)r0 * 128 + ko);
                if (v1) a1 = *(const short8*)(X + (size_t)r1 * 128 + ko);
                #pragma unroll
                for (int j = 0; j < 4; ++j) {
                    const short8 bf = *(const short8*)(W1 + (size_t)(cb + j * 16 + lrow) * 128 + ko);
                    acc[0][j] = __builtin_amdgcn_mfma_f32_16x16x32_bf16(a0, bf, acc[0][j], 0, 0, 0);
                    acc[1][j] = __builtin_amdgcn_mfma_f32_16x16x32_bf16(a1, bf, acc[1][j], 0, 0, 0);
                }
            }
            float bc[4];
            #pragma unroll
            for (int j = 0; j < 4; ++j) bc[j] = b1[cb + j * 16 + lrow];
            #pragma unroll
            for (int i = 0; i < 2; ++i) {
                #pragma unroll
                for (int r = 0; r < 4; ++r) {
                    const int lrel = i * 16 + quad * 4 + r;
                    #pragma unroll
                    for (int j = 0; j < 4; ++j)
                        Hs[lrel * HP + lcb + j * 16 + lrow] =
                            f2b(fmaxf(acc[i][j][r] + bc[j], 0.f));
                }
            }
        }
        __syncthreads();

        #pragma unroll
        for (int k0 = 0; k0 < 256; k0 += 32) {
            const int ko = k0 + quad * 8;                 // chunk-local k
            const int kw = chunk * 256 + ko;              // global k for W2
            const short8 a0 = *(const short8*)&Hs[lrow * HP + ko];
            const short8 a1 = *(const short8*)&Hs[(16 + lrow) * HP + ko];
            #pragma unroll
            for (int j = 0; j < 2; ++j) {
                const short8 bf = *(const short8*)(W2 + (size_t)(c0 + j * 16 + lrow) * 512 + kw);
                acc2[0][j] = __builtin_amdgcn_mfma_f32_16x16x32_bf16(a0, bf, acc2[0][j], 0, 0, 0);
                acc2[1][j] = __builtin_amdgcn_mfma_f32_16x16x32_bf16(a1, bf, acc2[1][j], 0, 0, 0);
            }
        }
        __syncthreads();
    }

    float bcol[2], gcol[2], bec[2];
    #pragma unroll
    for (int j = 0; j < 2; ++j) {
        const int col = c0 + j * 16 + lrow;
        bcol[j] = b2[col];
        gcol[j] = g[col];
        bec[j]  = be[col];
    }

    float vals[2][2][4];
    #pragma unroll
    for (int i = 0; i < 2; ++i) {
        #pragma unroll
        for (int r = 0; r < 4; ++r) {
            const int lrel = i * 16 + quad * 4 + r;
            const int row = m0 + lrel;
            const bool vr = row < M;
            float s = 0.f, s2 = 0.f;
            #pragma unroll
            for (int j = 0; j < 2; ++j) {
                const int col = c0 + j * 16 + lrow;
                float v = acc2[i][j][r] + bcol[j];
                if (vr) v += resid[(size_t)row * 128 + col];
                vals[i][j][r] = v;
                s += v; s2 += v * v;
            }
            s  += __shfl_xor(s, 1);  s  += __shfl_xor(s, 2);
            s  += __shfl_xor(s, 4);  s  += __shfl_xor(s, 8);
            s2 += __shfl_xor(s2, 1); s2 += __shfl_xor(s2, 2);
            s2 += __shfl_xor(s2, 4); s2 += __shfl_xor(s2, 8);
            if (lrow == 0) { psum[lrel][wave][0] = s; psum[lrel][wave][1] = s2; }
        }
    }
    __syncthreads();
    if (tid < 32) {
        const float sum   = psum[tid][0][0] + psum[tid][1][0] + psum[tid][2][0] + psum[tid][3][0];
        const float sumsq = psum[tid][0][1] + psum[tid][1][1] + psum[tid][2][1] + psum[tid][3][1];
        const float mean = sum * (1.f / 128.f);
        const float var  = sumsq * (1.f / 128.f) - mean * mean;
        stats[tid][0] = mean;
        stats[tid][1] = rsqrtf(var + 1e-5f);
    }
    __syncthreads();

    #pragma unroll
    for (int i = 0; i < 2; ++i) {
        #pragma unroll
        for (int r = 0; r < 4; ++r) {
            const int lrel = i * 16 + quad * 4 + r;
            const int row = m0 + lrel;
            if (row < M) {
                const float mean = stats[lrel][0];
                const float rstd = stats[lrel][1];
                #pragma unroll
                for (int j = 0; j < 2; ++j) {
                    const int col = c0 + j * 16 + lrow;
                    const float o = (vals[i][j][r] - mean) * rstd * gcol[j] + bec[j];
                    hF[(size_t)row * 128 + col] = o;
                    hB[(size_t)row * 128 + col] = f2b(o);
                }
            }
        }
    }
}

// ---------------------------------------------------------------------------
// attn_fused = sampled attention + out-proj + resid + LN1 (verified R13/R14).
// ---------------------------------------------------------------------------
__global__ __launch_bounds__(256) void attn_fused(
    const unsigned short* __restrict__ qkv, const int* __restrict__ samples,
    const unsigned* __restrict__ WoP,   // [2 planes][64 k2][64 j] packed pairs
    const float* __restrict__ bo,
    const float* __restrict__ g, const float* __restrict__ be,
    float* __restrict__ hF, unsigned short* __restrict__ hB, int n)
{
    __shared__ unsigned ctxs[4][64];    // packed bf16 ctx pairs per wave
    const int wv = threadIdx.x >> 6;
    const int lane = threadIdx.x & 63;
    const int node0 = blockIdx.x * 4 + wv;
    const bool live = node0 < n;
    const int node = live ? node0 : (n - 1);   // clamp; stores guarded by live
    const int s4 = lane >> 4;
    const int p  = lane & 15;
    const float scale = 0.17677669529663687f;  // 1/sqrt(32)

    // prefetch own-row residual (consumed only after the matvec)
    const size_t base = (size_t)node * 128;
    const float res0 = hF[base + lane];
    const float res1 = hF[base + lane + 64];

    const uint4 qu = *(const uint4*)(qkv + (size_t)node * 384 + p * 8);

    int rows[5];
    #pragma unroll
    for (int jj = 0; jj < 5; ++jj)
        rows[jj] = samples[node * KS + jj * 4 + s4];

    uint4 kus[5], vus[5];
    #pragma unroll
    for (int jj = 0; jj < 5; ++jj) {
        const size_t rb = (size_t)rows[jj] * 384 + p * 8;
        kus[jj] = *(const uint4*)(qkv + rb + 128);
        vus[jj] = *(const uint4*)(qkv + rb + 256);
    }

    float sc[5];
    #pragma unroll
    for (int jj = 0; jj < 5; ++jj) {
        const uint4 ku = kus[jj];
        float d = dot2bf(qu.x, ku.x, 0.f);
        d = dot2bf(qu.y, ku.y, d);
        d = dot2bf(qu.z, ku.z, d);
        d = dot2bf(qu.w, ku.w, d);
        d += __shfl_xor(d, 1);
        d += __shfl_xor(d, 2);
        sc[jj] = d * scale;
    }

    float m = sc[0];
    #pragma unroll
    for (int jj = 1; jj < 5; ++jj) m = fmaxf(m, sc[jj]);
    m = fmaxf(m, __shfl_xor(m, 16));
    m = fmaxf(m, __shfl_xor(m, 32));

    float l = 0.f;
    float o[8] = {};
    #pragma unroll
    for (int jj = 0; jj < 5; ++jj) {
        const float e = __expf(sc[jj] - m);
        l += e;
        const uint4 vu = vus[jj];
        o[0] += e * blo(vu.x); o[1] += e * bhi(vu.x);
        o[2] += e * blo(vu.y); o[3] += e * bhi(vu.y);
        o[4] += e * blo(vu.z); o[5] += e * bhi(vu.z);
        o[6] += e * blo(vu.w); o[7] += e * bhi(vu.w);
    }

    l += __shfl_xor(l, 16); l += __shfl_xor(l, 32);
    #pragma unroll
    for (int i = 0; i < 8; ++i) {
        o[i] += __shfl_xor(o[i], 16);
        o[i] += __shfl_xor(o[i], 32);
    }

    const float inv = 1.f / l;
    if (s4 == 0) {
        #pragma unroll
        for (int i = 0; i < 4; ++i)
            ctxs[wv][p * 4 + i] = pk(o[2 * i] * inv, o[2 * i + 1] * inv);
    }
    __syncthreads();

    // ---- out-proj matvec: lane -> cols {lane, lane+64}, dot2 ----
    const unsigned* Wa = WoP;           // cols 0..63
    const unsigned* Wb = WoP + 4096;    // cols 64..127
    float a0 = 0.f, a1 = 0.f;
    #pragma unroll 8
    for (int k2 = 0; k2 < 64; ++k2) {
        const unsigned c = ctxs[wv][k2];
        a0 = dot2bf(Wa[k2 * 64 + lane], c, a0);
        a1 = dot2bf(Wb[k2 * 64 + lane], c, a1);
    }

    // ---- resid + LN (verified resln pattern: lane / lane+64) ----
    float v0 = a0 + bo[lane]      + res0;
    float v1 = a1 + bo[lane + 64] + res1;
    float s = v0 + v1;
    #pragma unroll
    for (int mm = 32; mm >= 1; mm >>= 1) s += __shfl_xor(s, mm, 64);
    const float mean = s * (1.f / 128.f);
    const float d0 = v0 - mean, d1 = v1 - mean;
    float vs = d0 * d0 + d1 * d1;
    #pragma unroll
    for (int mm = 32; mm >= 1; mm >>= 1) vs += __shfl_xor(vs, mm, 64);
    const float rstd = rsqrtf(vs * (1.f / 128.f) + 1e-5f);
    if (live) {
        const float o0 = d0 * rstd * g[lane]      + be[lane];
        const float o1 = d1 * rstd * g[lane + 64] + be[lane + 64];
        hF[base + lane]      = o0;      hF[base + lane + 64] = o1;
        hB[base + lane]      = f2b(o0); hB[base + lane + 64] = f2b(o1);
    }
}

// ---------------------------------------------------------------------------
// Aggregation: wave/node, 4 edge slots x 4-deep unroll (16 loads in flight).
// (verified R14 @ ~70us. R15's 8-deep variant REGRESSED: mean degree 32 means
// the 32-stride main loop needs degree>=~116 to trigger — nearly all nodes
// fell to the 1-deep tail. Unroll depth must match trip count.)
// ---------------------------------------------------------------------------
__global__ __launch_bounds__(256) void aggregate_kernel(
    const unsigned short* __restrict__ hb, const int* __restrict__ offs,
    const int* __restrict__ csr, unsigned short* __restrict__ outp, int n, int E)
{
    const int node = blockIdx.x * 4 + (threadIdx.x >> 6);
    const int lane = threadIdx.x & 63;
    if (node >= n) return;
    const int e4 = lane >> 4;
    const int p  = lane & 15;
    const int s = offs[node];
    const int e = (node == n - 1) ? E : offs[node + 1];
    float a[8] = {};
    int i = s + e4;
    for (; i + 12 < e; i += 16) {
        const int d0 = csr[i], d1 = csr[i + 4], d2 = csr[i + 8], d3 = csr[i + 12];
        const uint4 u0 = *(const uint4*)(hb + (size_t)d0 * 128 + p * 8);
        const uint4 u1 = *(const uint4*)(hb + (size_t)d1 * 128 + p * 8);
        const uint4 u2 = *(const uint4*)(hb + (size_t)d2 * 128 + p * 8);
        const uint4 u3 = *(const uint4*)(hb + (size_t)d3 * 128 + p * 8);
        a[0] += blo(u0.x) + blo(u1.x) + blo(u2.x) + blo(u3.x);
        a[1] += bhi(u0.x) + bhi(u1.x) + bhi(u2.x) + bhi(u3.x);
        a[2] += blo(u0.y) + blo(u1.y) + blo(u2.y) + blo(u3.y);
        a[3] += bhi(u0.y) + bhi(u1.y) + bhi(u2.y) + bhi(u3.y);
        a[4] += blo(u0.z) + blo(u1.z) + blo(u2.z) + blo(u3.z);
        a[5] += bhi(u0.z) + bhi(u1.z) + bhi(u2.z) + bhi(u3.z);
        a[6] += blo(u0.w) + blo(u1.w) + blo(u2.w) + blo(u3.w);
        a[7] += bhi(u0.w) + bhi(u1.w) + bhi(u2.w) + bhi(u3.w);
    }
    for (; i < e; i += 4) {
        const uint4 u = *(const uint4*)(hb + (size_t)csr[i] * 128 + p * 8);
        a[0] += blo(u.x); a[1] += bhi(u.x);
        a[2] += blo(u.y); a[3] += bhi(u.y);
        a[4] += blo(u.z); a[5] += bhi(u.z);
        a[6] += blo(u.w); a[7] += bhi(u.w);
    }
    #pragma unroll
    for (int k = 0; k < 8; ++k) {
        a[k] += __shfl_xor(a[k], 16);
        a[k] += __shfl_xor(a[k], 32);
    }
    if (e4 == 0) {
        uint4 ow;
        ow.x = pk(a[0], a[1]); ow.y = pk(a[2], a[3]);
        ow.z = pk(a[4], a[5]); ow.w = pk(a[6], a[7]);
        *(uint4*)(outp + (size_t)node * 128 + p * 8) = ow;
    }
}

// ---------------------------------------------------------------------------
// Bucketed CSR build. (verified R4)
// ---------------------------------------------------------------------------
__global__ __launch_bounds__(256) void bcount_kernel(
    const int* __restrict__ esrc, int* __restrict__ bcnt, int E)
{
    __shared__ int hist[MAXB];
    for (int i = threadIdx.x; i < MAXB; i += 256) hist[i] = 0;
    __syncthreads();
    const int stride = gridDim.x * 256;
    for (int e = blockIdx.x * 256 + threadIdx.x; e < E; e += stride)
        atomicAdd(&hist[esrc[e] >> BSH], 1);
    __syncthreads();
    for (int i = threadIdx.x; i < MAXB; i += 256)
        if (hist[i]) atomicAdd(&bcnt[i], hist[i]);
}

__global__ void bscan_kernel(const int* __restrict__ bcnt, int* __restrict__ boffs,
                             int* __restrict__ bcur, int NB)
{
    if (threadIdx.x == 0 && blockIdx.x == 0) {
        int run = 0;
        for (int i = 0; i < NB; ++i) { boffs[i] = run; bcur[i] = run; run += bcnt[i]; }
        boffs[NB] = run;
    }
}

__global__ __launch_bounds__(256) void bscatter_kernel(
    const int* __restrict__ esrc, const int* __restrict__ edst,
    int* __restrict__ bcur, uint2* __restrict__ ebuck, int E)
{
    __shared__ int hist[MAXB], scanb[MAXB], lstart[MAXB], gbase[MAXB], cnt2[MAXB];
    __shared__ uint2 stage[2048];
    __shared__ int gaddr[2048];
    const int t = threadIdx.x;
    const int base = blockIdx.x * 2048;
    const int nchunk = min(2048, E - base);
    for (int i = t; i < MAXB; i += 256) { hist[i] = 0; cnt2[i] = 0; }
    __syncthreads();

    int es[8], ed[8], eb[8];
    #pragma unroll
    for (int i = 0; i < 8; ++i) {
        const int idx = base + i * 256 + t;
        if (idx < E) {
            es[i] = esrc[idx]; ed[i] = edst[idx];
            eb[i] = es[i] >> BSH;
            atomicAdd(&hist[eb[i]], 1);
        } else eb[i] = -1;
    }
    __syncthreads();

    if (t < MAXB) scanb[t] = hist[t];
    __syncthreads();
    for (int off = 1; off < MAXB; off <<= 1) {
        int v = 0;
        if (t < MAXB && t >= off) v = scanb[t - off];
        __syncthreads();
        if (t < MAXB) scanb[t] += v;
        __syncthreads();
    }
    if (t < MAXB) {
        lstart[t] = scanb[t] - hist[t];
        if (hist[t] > 0) gbase[t] = atomicAdd(&bcur[t], hist[t]);
    }
    __syncthreads();

    #pragma unroll
    for (int i = 0; i < 8; ++i) {
        if (eb[i] >= 0) {
            const int li = atomicAdd(&cnt2[eb[i]], 1);
            const int pos = lstart[eb[i]] + li;
            stage[pos] = make_uint2((unsigned)es[i], (unsigned)ed[i]);
            gaddr[pos] = gbase[eb[i]] + li;
        }
    }
    __syncthreads();
    for (int i = t; i < nchunk; i += 256)
        ebuck[gaddr[i]] = stage[i];
}

__global__ __launch_bounds__(256) void bbuild_kernel(
    const uint2* __restrict__ ebuck, const int* __restrict__ bcnt,
    const int* __restrict__ boffs, int* __restrict__ offs, int* __restrict__ csr, int N)
{
    __shared__ int degl[BW], sbuf[BW], curl[BW];
    const int b = blockIdx.x;
    const int t = threadIdx.x;
    const int nbase = b * BW;
    const int nn = min(BW, N - nbase);
    const int estart = boffs[b];
    const int ecnt = bcnt[b];

    for (int i = t; i < BW; i += 256) { degl[i] = 0; curl[i] = 0; }
    __syncthreads();
    for (int i = t; i < ecnt; i += 256)
        atomicAdd(&degl[(int)ebuck[estart + i].x - nbase], 1);
    __syncthreads();

    sbuf[t] = degl[t]; sbuf[t + 256] = degl[t + 256];
    __syncthreads();
    for (int off = 1; off < BW; off <<= 1) {
        const int i1 = t + 256;
        int v0 = (t  >= off) ? sbuf[t  - off] : 0;
        int v1 = (i1 >= off) ? sbuf[i1 - off] : 0;
        __syncthreads();
        sbuf[t] += v0; sbuf[i1] += v1;
        __syncthreads();
    }
    {
        const int e0 = sbuf[t] - degl[t];
        const int e1 = sbuf[t + 256] - degl[t + 256];
        sbuf[t] = e0; sbuf[t + 256] = e1;
        if (t < nn)       offs[nbase + t]       = estart + e0;
        if (t + 256 < nn) offs[nbase + t + 256] = estart + e1;
    }
    __syncthreads();
    for (int i = t; i < ecnt; i += 256) {
        const uint2 pr = ebuck[estart + i];
        const int s = (int)pr.x - nbase;
        const int pos = estart + sbuf[s] + atomicAdd(&curl[s], 1);
        csr[pos] = (int)pr.y;
    }
}

// ---------------------------------------------------------------------------
extern "C" void kernel_launch(void* const* d_in, const int* in_sizes, int n_in,
                              void* d_out, int out_size, void* d_ws, size_t ws_size,
                              hipStream_t stream)
{
    const float* x        = (const float*)d_in[0];
    const int*   samples  = (const int*)d_in[1];
    const int*   esrc     = (const int*)d_in[2];
    const int*   edst     = (const int*)d_in[3];
    const float* t_in_w   = (const float*)d_in[4];   // [3][384][128]
    const float* t_in_b   = (const float*)d_in[5];
    const float* t_out_w  = (const float*)d_in[6];   // [3][128][128]
    const float* t_out_b  = (const float*)d_in[7];
    const float* t_ffn_w1 = (const float*)d_in[8];   // [3][512][128]
    const float* t_ffn_b1 = (const float*)d_in[9];
    const float* t_ffn_w2 = (const float*)d_in[10];  // [3][128][512]
    const float* t_ffn_b2 = (const float*)d_in[11];
    const float* t_ln1_g  = (const float*)d_in[12];
    const float* t_ln1_b  = (const float*)d_in[13];
    const float* t_ln2_g  = (const float*)d_in[14];
    const float* t_ln2_b  = (const float*)d_in[15];
    const float* g_w      = (const float*)d_in[16];  // [2][128][256]
    const float* g_b      = (const float*)d_in[17];
    const float* g_ln_g   = (const float*)d_in[18];
    const float* g_ln_b   = (const float*)d_in[19];

    const int N = in_sizes[0] / DM;
    const int E = in_sizes[2];
    const int NB = (N + BW - 1) >> BSH;

    float* h = (float*)d_out;                        // [N][128] fp32 hidden

    // ---- workspace layout ----
    unsigned short* wbuf = (unsigned short*)d_ws;    // bf16 weights
    unsigned short* w_in  = wbuf;                    // 3*384*128 = 147456
    unsigned short* w_out = w_in  + 147456;          // 3*128*128 = 49152 (unused)
    unsigned short* w_f1  = w_out + 49152;           // 3*512*128 = 196608
    unsigned short* w_f2  = w_f1  + 196608;          // 3*128*512 = 196608
    unsigned short* w_g   = w_f2  + 196608;          // 2*128*256 = 65536
    unsigned* WoP = (unsigned*)(w_g + 65536);        // 3*8192 uints (packed pairs)
    unsigned short* hb  = (unsigned short*)(WoP + 3 * 8192);   // [N][128] bf16
    unsigned short* Bbf = hb  + (size_t)N * 128;     // [N][128] neigh
    unsigned short* Abf = Bbf + (size_t)N * 128;     // [N][384] QKV
    uint2* ebuck = (uint2*)(Abf + (size_t)N * 384);  // [E]
    int* offs = (int*)(ebuck + E);                   // [N]
    int* csr  = offs + N;                            // [E]
    int* bcnt  = csr + E;                            // [MAXB]
    int* boffs = bcnt + MAXB;                        // [MAXB+1]
    int* bcur  = boffs + MAXB + 1;                   // [MAXB]

    const int mt  = (N + 63) / 64;
    const int mt2 = (N + 127) / 128;
    const int mtf = (N + 31) / 32;
    const dim3 blk(256);

    xcvt_kernel<<<((N * DM) / 4 + 255) / 256, blk, 0, stream>>>(x, h, hb, N * DM);
    setup_kernel<<<(163840 + 24576 + MAXB + 255) / 256, blk, 0, stream>>>(
        t_in_w, t_out_w, t_ffn_w1, t_ffn_w2, g_w, wbuf, WoP, bcnt);

    // ---- bucketed CSR build (bcnt zeroed by setup_kernel) ----
    bcount_kernel<<<(E + 2047) / 2048, blk, 0, stream>>>(esrc, bcnt, E);
    bscan_kernel<<<1, 64, 0, stream>>>(bcnt, boffs, bcur, NB);
    bscatter_kernel<<<(E + 2047) / 2048, blk, 0, stream>>>(esrc, edst, bcur, ebuck, E);
    bbuild_kernel<<<NB, blk, 0, stream>>>(ebuck, bcnt, boffs, offs, csr, N);

    const int pn_grid = (N + 3) / 4;

    for (int layer = 0; layer < 5; ++layer) {
        if (layer == 1 || layer == 3) {
            // -------- GNN block: split (R14 — fused variant was slower) -----
            const int i = (layer == 1) ? 0 : 1;
            aggregate_kernel<<<pn_grid, blk, 0, stream>>>(hb, offs, csr, Bbf, N, E);
            gemm_ln<256, true, 128><<<mt, blk, 0, stream>>>(
                hb, Bbf, w_g + (size_t)i * 32768, g_b + i * 128, h,
                g_ln_g + i * 128, g_ln_b + i * 128, h, hb, N);
        } else {
            // ---------------- Transformer block: 3 kernels ----------------
            const int i = (layer == 0) ? 0 : (layer == 2 ? 1 : 2);
            gemm_mfma<128, 384, false><<<dim3(mt2, 6), blk, 0, stream>>>(
                hb, w_in + (size_t)i * 49152, t_in_b + i * 384, Abf, N);
            attn_fused<<<pn_grid, blk, 0, stream>>>(
                Abf, samples, WoP + (size_t)i * 8192, t_out_b + i * 128,
                t_ln1_g + i * 128, t_ln1_b + i * 128, h, hb, N);
            ffn_fused<<<mtf, blk, 0, stream>>>(
                hb, w_f1 + (size_t)i * 65536, t_ffn_b1 + i * 512,
                w_f2 + (size_t)i * 65536, t_ffn_b2 + i * 128, h,
                t_ln2_g + i * 128, t_ln2_b + i * 128, h, hb, N);
        }
    }
}